// Round 1
// baseline (1273.489 us; speedup 1.0000x reference)
//
#include <hip/hip_runtime.h>
#include <cstddef>
#include <cstdint>

#define BB 4
#define NN 6144
#define DD 64
#define HID 512
#define OUTD 64

// ws layout: [0, BB*NN*8) u64 packed col-max (key<<32 | argmax_n); then BB*NN int match12

__device__ __forceinline__ unsigned int fkey(float v) {
    unsigned int u = __float_as_uint(v);
    return (u & 0x80000000u) ? ~u : (u | 0x80000000u);
}

__global__ void init_ws_kernel(unsigned long long* colmax) {
    int i = blockIdx.x * blockDim.x + threadIdx.x;
    if (i < BB * NN) colmax[i] = 0ULL;
}

// --- Kernel A: tiled cosine-sim, row argmax (match12) + packed atomic col argmax ---
__global__ __launch_bounds__(256) void sim_argmax_kernel(
    const float* __restrict__ f1, const float* __restrict__ f2,
    unsigned long long* __restrict__ colmax, int* __restrict__ match12)
{
    const int b   = blockIdx.y;
    const int r0  = blockIdx.x * 64;
    const int tid = threadIdx.x;
    const int rg  = tid >> 4;   // 0..15 row-groups, rows rg + 16*i
    const int cg  = tid & 15;   // 0..15 col-groups, cols cg + 16*j

    __shared__ float s1[64 * 68];   // pad 68: 16B-aligned rows, conflict-free b128 reads
    __shared__ float s2[64 * 68];
    __shared__ float rv[64 * 16];
    __shared__ int   ri[64 * 16];

    const float* f1base = f1 + ((size_t)b * NN + r0) * DD;
    #pragma unroll
    for (int pass = 0; pass < 4; ++pass) {
        int idx = pass * 256 + tid;
        int row = idx >> 4, c4 = idx & 15;
        float4 v = *reinterpret_cast<const float4*>(f1base + row * DD + c4 * 4);
        *reinterpret_cast<float4*>(&s1[row * 68 + c4 * 4]) = v;
    }

    float bestv[4];
    int   besti[4];
    #pragma unroll
    for (int i = 0; i < 4; ++i) { bestv[i] = -2.0f; besti[i] = 0; }

    for (int m0 = 0; m0 < NN; m0 += 64) {
        __syncthreads();  // protect s2 + rv/ri reuse
        const float* f2base = f2 + ((size_t)b * NN + m0) * DD;
        #pragma unroll
        for (int pass = 0; pass < 4; ++pass) {
            int idx = pass * 256 + tid;
            int row = idx >> 4, c4 = idx & 15;
            float4 v = *reinterpret_cast<const float4*>(f2base + row * DD + c4 * 4);
            *reinterpret_cast<float4*>(&s2[row * 68 + c4 * 4]) = v;
        }
        __syncthreads();

        float acc[4][4];
        #pragma unroll
        for (int i = 0; i < 4; ++i)
            #pragma unroll
            for (int j = 0; j < 4; ++j) acc[i][j] = 0.0f;

        #pragma unroll 4
        for (int k = 0; k < DD; k += 4) {
            float a[4][4], bb2[4][4];
            #pragma unroll
            for (int i = 0; i < 4; ++i) {
                float4 v = *reinterpret_cast<const float4*>(&s1[(rg + 16 * i) * 68 + k]);
                a[i][0] = v.x; a[i][1] = v.y; a[i][2] = v.z; a[i][3] = v.w;
            }
            #pragma unroll
            for (int j = 0; j < 4; ++j) {
                float4 v = *reinterpret_cast<const float4*>(&s2[(cg + 16 * j) * 68 + k]);
                bb2[j][0] = v.x; bb2[j][1] = v.y; bb2[j][2] = v.z; bb2[j][3] = v.w;
            }
            #pragma unroll
            for (int kk = 0; kk < 4; ++kk)
                #pragma unroll
                for (int i = 0; i < 4; ++i)
                    #pragma unroll
                    for (int j = 0; j < 4; ++j)
                        acc[i][j] = fmaf(a[i][kk], bb2[j][kk], acc[i][j]);
        }

        // row-best update (this chunk's cols), first-occurrence tie semantics via >
        #pragma unroll
        for (int i = 0; i < 4; ++i)
            #pragma unroll
            for (int j = 0; j < 4; ++j) {
                int m = m0 + cg + 16 * j;
                if (acc[i][j] > bestv[i]) { bestv[i] = acc[i][j]; besti[i] = m; }
            }

        // col-best: local over this thread's 4 rows, then LDS reduce + atomic merge
        #pragma unroll
        for (int j = 0; j < 4; ++j) {
            float v = acc[0][j]; int r = rg;
            #pragma unroll
            for (int i = 1; i < 4; ++i)
                if (acc[i][j] > v) { v = acc[i][j]; r = rg + 16 * i; }
            rv[(cg + 16 * j) * 16 + rg] = v;
            ri[(cg + 16 * j) * 16 + rg] = r0 + r;
        }
        __syncthreads();
        if (tid < 64) {
            float v = rv[tid * 16]; int n = ri[tid * 16];
            #pragma unroll
            for (int g = 1; g < 16; ++g) {
                float v2 = rv[tid * 16 + g];
                int   n2 = ri[tid * 16 + g];
                if (v2 > v || (v2 == v && n2 < n)) { v = v2; n = n2; }
            }
            unsigned long long pk =
                ((unsigned long long)fkey(v) << 32) | (unsigned int)n;
            atomicMax(&colmax[(size_t)b * NN + m0 + tid], pk);
        }
    }

    __syncthreads();
    #pragma unroll
    for (int i = 0; i < 4; ++i) {
        rv[(rg + 16 * i) * 16 + cg] = bestv[i];
        ri[(rg + 16 * i) * 16 + cg] = besti[i];
    }
    __syncthreads();
    if (tid < 64) {
        float v = rv[tid * 16]; int m = ri[tid * 16];
        #pragma unroll
        for (int g = 1; g < 16; ++g) {
            float v2 = rv[tid * 16 + g];
            int   m2 = ri[tid * 16 + g];
            if (v2 > v || (v2 == v && m2 < m)) { v = v2; m = m2; }
        }
        match12[(size_t)b * NN + r0 + tid] = m;
    }
}

// --- Kernel B: fused 5-layer MLP (32 pts/block, acts in LDS) + softmax/subpix epilogue ---
__device__ __forceinline__ void mlp_layer512(
    float* act, const float* __restrict__ W, const float* __restrict__ bias,
    int K, int t)
{
    const int jg = t & 63;   // 64 groups * 8 outputs
    const int pg = t >> 6;   // 4 groups * 8 points
    float acc[8][8];
    #pragma unroll
    for (int p = 0; p < 8; ++p)
        #pragma unroll
        for (int j = 0; j < 8; ++j) acc[p][j] = 0.0f;

    for (int k = 0; k < K; k += 4) {
        float a[8][4];
        #pragma unroll
        for (int p = 0; p < 8; ++p) {
            float4 v = *reinterpret_cast<const float4*>(&act[(pg * 8 + p) * HID + k]);
            a[p][0] = v.x; a[p][1] = v.y; a[p][2] = v.z; a[p][3] = v.w;
        }
        #pragma unroll
        for (int kk = 0; kk < 4; ++kk) {
            float4 wa = *reinterpret_cast<const float4*>(&W[(size_t)(k + kk) * HID + jg * 8]);
            float4 wb = *reinterpret_cast<const float4*>(&W[(size_t)(k + kk) * HID + jg * 8 + 4]);
            #pragma unroll
            for (int p = 0; p < 8; ++p) {
                acc[p][0] = fmaf(a[p][kk], wa.x, acc[p][0]);
                acc[p][1] = fmaf(a[p][kk], wa.y, acc[p][1]);
                acc[p][2] = fmaf(a[p][kk], wa.z, acc[p][2]);
                acc[p][3] = fmaf(a[p][kk], wa.w, acc[p][3]);
                acc[p][4] = fmaf(a[p][kk], wb.x, acc[p][4]);
                acc[p][5] = fmaf(a[p][kk], wb.y, acc[p][5]);
                acc[p][6] = fmaf(a[p][kk], wb.z, acc[p][6]);
                acc[p][7] = fmaf(a[p][kk], wb.w, acc[p][7]);
            }
        }
    }
    __syncthreads();  // all reads of act done before in-place overwrite
    float4 bv0 = *reinterpret_cast<const float4*>(&bias[jg * 8]);
    float4 bv1 = *reinterpret_cast<const float4*>(&bias[jg * 8 + 4]);
    #pragma unroll
    for (int p = 0; p < 8; ++p) {
        float4 o0, o1;
        o0.x = fmaxf(acc[p][0] + bv0.x, 0.0f);
        o0.y = fmaxf(acc[p][1] + bv0.y, 0.0f);
        o0.z = fmaxf(acc[p][2] + bv0.z, 0.0f);
        o0.w = fmaxf(acc[p][3] + bv0.w, 0.0f);
        o1.x = fmaxf(acc[p][4] + bv1.x, 0.0f);
        o1.y = fmaxf(acc[p][5] + bv1.y, 0.0f);
        o1.z = fmaxf(acc[p][6] + bv1.z, 0.0f);
        o1.w = fmaxf(acc[p][7] + bv1.w, 0.0f);
        *reinterpret_cast<float4*>(&act[(pg * 8 + p) * HID + jg * 8]) = o0;
        *reinterpret_cast<float4*>(&act[(pg * 8 + p) * HID + jg * 8 + 4]) = o1;
    }
    __syncthreads();
}

__global__ __launch_bounds__(256) void mlp_out_kernel(
    const float* __restrict__ f1, const float* __restrict__ f2,
    const float* __restrict__ kps1, const float* __restrict__ kps2,
    const float* __restrict__ scales1,
    const float* __restrict__ w1, const float* __restrict__ b1,
    const float* __restrict__ w2, const float* __restrict__ b2,
    const float* __restrict__ w3, const float* __restrict__ b3,
    const float* __restrict__ w4, const float* __restrict__ b4,
    const float* __restrict__ w5, const float* __restrict__ b5,
    const unsigned long long* __restrict__ colmax,
    const int* __restrict__ match12,
    float* __restrict__ out)
{
    __shared__ float act[32 * HID];   // 64 KB
    const int t    = threadIdx.x;
    const int base = blockIdx.x * 32;
    const int b    = base / NN;
    const int n0   = base % NN;

    // stage concat(feats1[n], feats2[match12[n]]) -> act[p][0..127]
    #pragma unroll
    for (int pass = 0; pass < 4; ++pass) {
        int q = pass * 256 + t;       // 1024 float4s, 32 per point
        int p = q >> 5, c4 = q & 31;
        int n = n0 + p;
        const float* src;
        if (c4 < 16) {
            src = f1 + ((size_t)b * NN + n) * DD + c4 * 4;
        } else {
            int m = match12[(size_t)b * NN + n];
            src = f2 + ((size_t)b * NN + m) * DD + (c4 - 16) * 4;
        }
        *reinterpret_cast<float4*>(&act[p * HID + c4 * 4]) =
            *reinterpret_cast<const float4*>(src);
    }
    __syncthreads();

    mlp_layer512(act, w1, b1, 2 * DD, t);
    mlp_layer512(act, w2, b2, HID, t);
    mlp_layer512(act, w3, b3, HID, t);
    mlp_layer512(act, w4, b4, HID, t);

    // layer 5: K=512 -> 64 outputs, no relu
    {
        const int jg = t & 7;    // 8 groups * 8 outputs
        const int pg = t >> 3;   // one point per thread-group
        float acc[8];
        #pragma unroll
        for (int j = 0; j < 8; ++j) acc[j] = 0.0f;
        for (int k = 0; k < HID; k += 4) {
            float a[4];
            float4 v = *reinterpret_cast<const float4*>(&act[pg * HID + k]);
            a[0] = v.x; a[1] = v.y; a[2] = v.z; a[3] = v.w;
            #pragma unroll
            for (int kk = 0; kk < 4; ++kk) {
                float4 wa = *reinterpret_cast<const float4*>(&w5[(size_t)(k + kk) * OUTD + jg * 8]);
                float4 wb = *reinterpret_cast<const float4*>(&w5[(size_t)(k + kk) * OUTD + jg * 8 + 4]);
                acc[0] = fmaf(a[kk], wa.x, acc[0]);
                acc[1] = fmaf(a[kk], wa.y, acc[1]);
                acc[2] = fmaf(a[kk], wa.z, acc[2]);
                acc[3] = fmaf(a[kk], wa.w, acc[3]);
                acc[4] = fmaf(a[kk], wb.x, acc[4]);
                acc[5] = fmaf(a[kk], wb.y, acc[5]);
                acc[6] = fmaf(a[kk], wb.z, acc[6]);
                acc[7] = fmaf(a[kk], wb.w, acc[7]);
            }
        }
        __syncthreads();
        float4 bv0 = *reinterpret_cast<const float4*>(&b5[jg * 8]);
        float4 bv1 = *reinterpret_cast<const float4*>(&b5[jg * 8 + 4]);
        float4 o0, o1;
        o0.x = acc[0] + bv0.x; o0.y = acc[1] + bv0.y;
        o0.z = acc[2] + bv0.z; o0.w = acc[3] + bv0.w;
        o1.x = acc[4] + bv1.x; o1.y = acc[5] + bv1.y;
        o1.z = acc[6] + bv1.z; o1.w = acc[7] + bv1.w;
        *reinterpret_cast<float4*>(&act[pg * HID + jg * 8]) = o0;
        *reinterpret_cast<float4*>(&act[pg * HID + jg * 8 + 4]) = o1;
        __syncthreads();
    }

    // epilogue: softmax(3*logits) -> conf, expected coords; gather + mutual + write
    if (t < 32) {
        const int p = t;
        const int n = n0 + p;
        const float* o = &act[p * HID];
        float mx = -1e30f;
        for (int j = 0; j < OUTD; ++j) mx = fmaxf(mx, 3.0f * o[j]);
        float s = 0.0f, cx = 0.0f, cy = 0.0f;
        for (int j = 0; j < OUTD; ++j) {
            float e = __expf(3.0f * o[j] - mx);
            s  += e;
            cx += e * (float)((j & 7) - 4);
            cy += e * (float)((j >> 3) - 4);
        }
        float conf = 1.0f / s;           // max heat = e^0 / s
        cx /= s; cy /= s;
        int m = match12[(size_t)b * NN + n];
        int back = (int)(unsigned int)(colmax[(size_t)b * NN + m] & 0xffffffffULL);
        bool mutual = (back == n);
        float sc = scales1[(size_t)b * NN + n];
        float x0 = kps1[((size_t)b * NN + n) * 2 + 0] + cx * sc;
        float y0 = kps1[((size_t)b * NN + n) * 2 + 1] + cy * sc;
        float x1 = kps2[((size_t)b * NN + m) * 2 + 0];
        float y1 = kps2[((size_t)b * NN + m) * 2 + 1];
        float* mt = out + ((size_t)b * NN + n) * 4;
        mt[0] = x0; mt[1] = y0; mt[2] = x1; mt[3] = y1;
        out[(size_t)BB * NN * 4 + (size_t)b * NN + n] =
            (mutual && conf > 0.25f) ? 1.0f : 0.0f;
    }
}

extern "C" void kernel_launch(void* const* d_in, const int* in_sizes, int n_in,
                              void* d_out, int out_size, void* d_ws, size_t ws_size,
                              hipStream_t stream)
{
    const float* f1  = (const float*)d_in[0];
    const float* f2  = (const float*)d_in[1];
    const float* kp1 = (const float*)d_in[2];
    const float* kp2 = (const float*)d_in[3];
    const float* sc1 = (const float*)d_in[4];
    const float* w1  = (const float*)d_in[5];
    const float* b1  = (const float*)d_in[6];
    const float* w2  = (const float*)d_in[7];
    const float* b2  = (const float*)d_in[8];
    const float* w3  = (const float*)d_in[9];
    const float* b3  = (const float*)d_in[10];
    const float* w4  = (const float*)d_in[11];
    const float* b4  = (const float*)d_in[12];
    const float* w5  = (const float*)d_in[13];
    const float* b5  = (const float*)d_in[14];

    unsigned long long* colmax = (unsigned long long*)d_ws;
    int* match12 = (int*)((char*)d_ws + (size_t)BB * NN * 8);
    float* out = (float*)d_out;

    init_ws_kernel<<<(BB * NN + 255) / 256, 256, 0, stream>>>(colmax);
    dim3 gA(NN / 64, BB);
    sim_argmax_kernel<<<gA, 256, 0, stream>>>(f1, f2, colmax, match12);
    mlp_out_kernel<<<(BB * NN) / 32, 256, 0, stream>>>(
        f1, f2, kp1, kp2, sc1, w1, b1, w2, b2, w3, b3, w4, b4, w5, b5,
        colmax, match12, out);
}

// Round 2
// 391.047 us; speedup vs baseline: 3.2566x; 3.2566x over previous
//
#include <hip/hip_runtime.h>
#include <cstddef>
#include <cstdint>

#define BB 4
#define NN 6144
#define DD 64
#define HID 512
#define OUTD 64
#define CSPLIT 8
#define NCHUNK (NN / CSPLIT / 128)   // 6

typedef unsigned long long ull;
typedef __attribute__((ext_vector_type(8))) short short8_t;
typedef __attribute__((ext_vector_type(4))) float floatx4;
typedef __attribute__((ext_vector_type(4))) unsigned short ushort4_t;

// ws layout (bytes):
//   [0, BB*NN*8)                      rowmax: packed u64  fkey(v)<<32 | ~col
//   [BB*NN*8, 2*BB*NN*8)              colmax: packed u64  fkey(v)<<32 | ~row
//   [2*BB*NN*8, +884736*2)            bf16 weights, MFMA-fragment-tiled
#define WS_WT_OFF ((size_t)2 * BB * NN * 8)
#define WT1_OFF 0
#define WT2_OFF 65536
#define WT3_OFF 327680
#define WT4_OFF 589824
#define WT5_OFF 851968
#define WT_TOTAL 884736

__device__ __forceinline__ unsigned int fkey(float v) {
    unsigned int u = __float_as_uint(v);
    return (u & 0x80000000u) ? ~u : (u | 0x80000000u);
}

__device__ __forceinline__ unsigned short f2bf(float f) {
    unsigned int u = __float_as_uint(f);
    u += 0x7FFFu + ((u >> 16) & 1u);
    return (unsigned short)(u >> 16);
}

__global__ void init_ws_kernel(ull* p) {
    int i = blockIdx.x * blockDim.x + threadIdx.x;
    if (i < 2 * BB * NN) p[i] = 0ULL;
}

// ---- convert fp32 weights -> bf16, MFMA-fragment-tiled: for (ch,k):
//   frag = (ch>>4)*(K/32) + (k>>5); lane = (ch&15) | (((k>>3)&3)<<4); j = k&7
//   wt[(frag*64 + lane)*8 + j]
__global__ __launch_bounds__(256) void convert_wt_kernel(
    const float* __restrict__ w1, const float* __restrict__ w2,
    const float* __restrict__ w3, const float* __restrict__ w4,
    const float* __restrict__ w5, unsigned short* __restrict__ wt)
{
    int idx = blockIdx.x * 256 + threadIdx.x;
    if (idx >= WT_TOTAL) return;
    const float* w; unsigned short* o; int K, nsh, li;
    if (idx < 65536)        { w = w1; o = wt + WT1_OFF; K = 128; nsh = 9; li = idx; }
    else if (idx < 327680)  { w = w2; o = wt + WT2_OFF; K = 512; nsh = 9; li = idx - 65536; }
    else if (idx < 589824)  { w = w3; o = wt + WT3_OFF; K = 512; nsh = 9; li = idx - 327680; }
    else if (idx < 851968)  { w = w4; o = wt + WT4_OFF; K = 512; nsh = 9; li = idx - 589824; }
    else                    { w = w5; o = wt + WT5_OFF; K = 512; nsh = 6; li = idx - 851968; }
    int k = li >> nsh;
    int n = li & ((1 << nsh) - 1);
    unsigned short v = f2bf(w[li]);
    int lane = (n & 15) | (((k >> 3) & 3) << 4);
    o[(((n >> 4) * (K >> 5) + (k >> 5)) * 64 + lane) * 8 + (k & 7)] = v;
}

// ---- Kernel A: fp32 tiled cosine-sim, 128x128 tile, 8x8 acc,
//      packed-u64 shfl reduce + atomicMax for row AND col argmax ----
__global__ __launch_bounds__(256, 2) void sim_kernel(
    const float* __restrict__ f1, const float* __restrict__ f2,
    ull* __restrict__ rowmax, ull* __restrict__ colmax)
{
    __shared__ float s1[128 * 68];
    __shared__ float s2[128 * 68];
    const int b  = blockIdx.z;
    const int r0 = blockIdx.x * 128;
    const int c0 = blockIdx.y * (NN / CSPLIT);
    const int tid = threadIdx.x;
    const int rg = tid >> 4;    // rows rg + 16*i
    const int cg = tid & 15;    // cols cg + 16*j

    const float* f1b = f1 + ((size_t)b * NN + r0) * DD;
    #pragma unroll
    for (int p = 0; p < 8; ++p) {
        int idx = p * 256 + tid;
        int row = idx >> 4, c4 = idx & 15;
        *reinterpret_cast<float4*>(&s1[row * 68 + c4 * 4]) =
            *reinterpret_cast<const float4*>(f1b + row * 64 + c4 * 4);
    }

    float bestv[8];
    int   besti[8];
    #pragma unroll
    for (int i = 0; i < 8; ++i) { bestv[i] = -2.0f; besti[i] = 0; }

    #pragma unroll 1
    for (int ch = 0; ch < NCHUNK; ++ch) {
        __syncthreads();
        const float* f2b = f2 + ((size_t)b * NN + c0 + ch * 128) * DD;
        #pragma unroll
        for (int p = 0; p < 8; ++p) {
            int idx = p * 256 + tid;
            int row = idx >> 4, c4 = idx & 15;
            *reinterpret_cast<float4*>(&s2[row * 68 + c4 * 4]) =
                *reinterpret_cast<const float4*>(f2b + row * 64 + c4 * 4);
        }
        __syncthreads();

        float acc[8][8];
        #pragma unroll
        for (int i = 0; i < 8; ++i)
            #pragma unroll
            for (int j = 0; j < 8; ++j) acc[i][j] = 0.0f;

        #pragma unroll 2
        for (int k = 0; k < 64; k += 4) {
            float a_[8][4], b_[8][4];
            #pragma unroll
            for (int i = 0; i < 8; ++i) {
                float4 v = *reinterpret_cast<const float4*>(&s1[(rg + 16 * i) * 68 + k]);
                a_[i][0] = v.x; a_[i][1] = v.y; a_[i][2] = v.z; a_[i][3] = v.w;
            }
            #pragma unroll
            for (int j = 0; j < 8; ++j) {
                float4 v = *reinterpret_cast<const float4*>(&s2[(cg + 16 * j) * 68 + k]);
                b_[j][0] = v.x; b_[j][1] = v.y; b_[j][2] = v.z; b_[j][3] = v.w;
            }
            #pragma unroll
            for (int kk = 0; kk < 4; ++kk)
                #pragma unroll
                for (int i = 0; i < 8; ++i)
                    #pragma unroll
                    for (int j = 0; j < 8; ++j)
                        acc[i][j] = fmaf(a_[i][kk], b_[j][kk], acc[i][j]);
        }

        // row-best update (cols ascending across j and ch; strict > keeps first)
        #pragma unroll
        for (int i = 0; i < 8; ++i)
            #pragma unroll
            for (int j = 0; j < 8; ++j) {
                int c = c0 + ch * 128 + cg + 16 * j;
                if (acc[i][j] > bestv[i]) { bestv[i] = acc[i][j]; besti[i] = c; }
            }

        // col-best: in-thread over rows, pack, wave shfl-reduce over rg, atomic
        #pragma unroll
        for (int j = 0; j < 8; ++j) {
            float v = acc[0][j]; int r = r0 + rg;
            #pragma unroll
            for (int i = 1; i < 8; ++i)
                if (acc[i][j] > v) { v = acc[i][j]; r = r0 + rg + 16 * i; }
            ull p = ((ull)fkey(v) << 32) | (unsigned int)(~(unsigned int)r);
            ull q;
            q = __shfl_xor(p, 16); p = p > q ? p : q;
            q = __shfl_xor(p, 32); p = p > q ? p : q;
            if ((tid & 63) < 16)
                atomicMax(&colmax[(size_t)b * NN + c0 + ch * 128 + cg + 16 * j], p);
        }
    }

    // final row merge over cg (lanes 0..15 of each 16-group)
    #pragma unroll
    for (int i = 0; i < 8; ++i) {
        ull p = ((ull)fkey(bestv[i]) << 32) | (unsigned int)(~(unsigned int)besti[i]);
        ull q;
        q = __shfl_xor(p, 1); p = p > q ? p : q;
        q = __shfl_xor(p, 2); p = p > q ? p : q;
        q = __shfl_xor(p, 4); p = p > q ? p : q;
        q = __shfl_xor(p, 8); p = p > q ? p : q;
        if (cg == 0)
            atomicMax(&rowmax[(size_t)b * NN + r0 + rg + 16 * i], p);
    }
}

// ---- Kernel B: bf16 MFMA MLP, 64 pts/block, acts in swizzled LDS ----
// act element (pt, k): 16B chunk index = k>>3, swizzled: chunk ^ (pt&7)
template<int K>
__device__ __forceinline__ void mlp_layer(
    unsigned short* act, const unsigned short* __restrict__ wt,
    const float* __restrict__ bias, int lane, int wid)
{
    floatx4 acc[8][4];
    #pragma unroll
    for (int ia = 0; ia < 8; ++ia)
        #pragma unroll
        for (int jb = 0; jb < 4; ++jb)
            acc[ia][jb] = (floatx4)(0.0f);

    const int l15 = lane & 15, l4 = lane >> 4;
    const int chBlk0 = wid * 8;   // (wid*128)/16

    #pragma unroll 2
    for (int kb = 0; kb < K / 32; ++kb) {
        short8_t bfr[4];
        #pragma unroll
        for (int jb = 0; jb < 4; ++jb) {
            int pt = jb * 16 + l15;
            int chk = (kb * 4 + l4) ^ (pt & 7);
            bfr[jb] = *reinterpret_cast<const short8_t*>(act + (pt * 64 + chk) * 8);
        }
        short8_t afr[8];
        #pragma unroll
        for (int ia = 0; ia < 8; ++ia)
            afr[ia] = *reinterpret_cast<const short8_t*>(
                wt + (((chBlk0 + ia) * (K / 32) + kb) * 64 + lane) * 8);
        #pragma unroll
        for (int ia = 0; ia < 8; ++ia)
            #pragma unroll
            for (int jb = 0; jb < 4; ++jb)
                acc[ia][jb] = __builtin_amdgcn_mfma_f32_16x16x32_bf16(
                    afr[ia], bfr[jb], acc[ia][jb], 0, 0, 0);
    }
    __syncthreads();   // all reads done before in-place overwrite

    const int ch0 = wid * 128;
    #pragma unroll
    for (int ia = 0; ia < 8; ++ia) {
        int cb = ia * 16 + l4 * 4;
        float4 bv = *reinterpret_cast<const float4*>(bias + ch0 + cb);
        #pragma unroll
        for (int jb = 0; jb < 4; ++jb) {
            int pt = jb * 16 + l15;
            ushort4_t h;
            h[0] = f2bf(fmaxf(acc[ia][jb][0] + bv.x, 0.0f));
            h[1] = f2bf(fmaxf(acc[ia][jb][1] + bv.y, 0.0f));
            h[2] = f2bf(fmaxf(acc[ia][jb][2] + bv.z, 0.0f));
            h[3] = f2bf(fmaxf(acc[ia][jb][3] + bv.w, 0.0f));
            int chk = ((ch0 + cb) >> 3) ^ (pt & 7);
            *reinterpret_cast<ushort4_t*>(act + (pt * 64 + chk) * 8 + (cb & 7)) = h;
        }
    }
    __syncthreads();
}

__global__ __launch_bounds__(256, 2) void mlp_mfma_kernel(
    const float* __restrict__ f1, const float* __restrict__ f2,
    const float* __restrict__ kps1, const float* __restrict__ kps2,
    const float* __restrict__ scales1,
    const float* __restrict__ b1, const float* __restrict__ b2,
    const float* __restrict__ b3, const float* __restrict__ b4,
    const float* __restrict__ b5,
    const unsigned short* __restrict__ wt,
    const ull* __restrict__ rowmax, const ull* __restrict__ colmax,
    float* __restrict__ out)
{
    __shared__ __align__(16) unsigned char lds_raw[65536];
    unsigned short* act = reinterpret_cast<unsigned short*>(lds_raw);
    float* logf = reinterpret_cast<float*>(lds_raw);

    const int t = threadIdx.x;
    const int lane = t & 63, wid = t >> 6;
    const int base = blockIdx.x * 64;
    const int b = base / NN;
    const int n0 = base % NN;

    // stage concat(f1[n], f2[match12[n]]) as bf16, swizzled
    {
        const int pt = t & 63, seg = t >> 6;
        const int n = n0 + pt;
        ull rm = rowmax[(size_t)b * NN + n];
        const int m = (int)(~(unsigned int)(rm & 0xffffffffULL));
        const float* src = (seg < 2)
            ? (f1 + ((size_t)b * NN + n) * DD + (seg & 1) * 32)
            : (f2 + ((size_t)b * NN + m) * DD + (seg & 1) * 32);
        #pragma unroll
        for (int q = 0; q < 4; ++q) {
            float4 v0 = *reinterpret_cast<const float4*>(src + q * 8);
            float4 v1 = *reinterpret_cast<const float4*>(src + q * 8 + 4);
            short8_t h;
            h[0] = (short)f2bf(v0.x); h[1] = (short)f2bf(v0.y);
            h[2] = (short)f2bf(v0.z); h[3] = (short)f2bf(v0.w);
            h[4] = (short)f2bf(v1.x); h[5] = (short)f2bf(v1.y);
            h[6] = (short)f2bf(v1.z); h[7] = (short)f2bf(v1.w);
            int chk = (seg * 4 + q) ^ (pt & 7);
            *reinterpret_cast<short8_t*>(act + (pt * 64 + chk) * 8) = h;
        }
    }
    __syncthreads();

    mlp_layer<128>(act, wt + WT1_OFF, b1, lane, wid);
    mlp_layer<512>(act, wt + WT2_OFF, b2, lane, wid);
    mlp_layer<512>(act, wt + WT3_OFF, b3, lane, wid);
    mlp_layer<512>(act, wt + WT4_OFF, b4, lane, wid);

    // layer 5: 512 -> 64, no relu; wave w handles channels [16w, 16w+16)
    {
        const int l15 = lane & 15, l4 = lane >> 4;
        floatx4 acc5[4];
        #pragma unroll
        for (int jb = 0; jb < 4; ++jb) acc5[jb] = (floatx4)(0.0f);
        #pragma unroll 2
        for (int kb = 0; kb < 16; ++kb) {
            short8_t bfr[4];
            #pragma unroll
            for (int jb = 0; jb < 4; ++jb) {
                int pt = jb * 16 + l15;
                int chk = (kb * 4 + l4) ^ (pt & 7);
                bfr[jb] = *reinterpret_cast<const short8_t*>(act + (pt * 64 + chk) * 8);
            }
            short8_t afr = *reinterpret_cast<const short8_t*>(
                wt + WT5_OFF + ((wid * 16 + kb) * 64 + lane) * 8);
            #pragma unroll
            for (int jb = 0; jb < 4; ++jb)
                acc5[jb] = __builtin_amdgcn_mfma_f32_16x16x32_bf16(
                    afr, bfr[jb], acc5[jb], 0, 0, 0);
        }
        __syncthreads();   // all act reads done; lds_raw becomes logits f32
        int cb = wid * 16 + l4 * 4;
        float4 bv = *reinterpret_cast<const float4*>(b5 + cb);
        #pragma unroll
        for (int jb = 0; jb < 4; ++jb) {
            int pt = jb * 16 + l15;
            float4 o;
            o.x = acc5[jb][0] + bv.x;
            o.y = acc5[jb][1] + bv.y;
            o.z = acc5[jb][2] + bv.z;
            o.w = acc5[jb][3] + bv.w;
            *reinterpret_cast<float4*>(&logf[pt * 68 + cb]) = o;
        }
        __syncthreads();
    }

    // epilogue: softmax(3*logits), conf, expected coords, gather, mutual, write
    if (t < 64) {
        const int pt = t;
        const int n = n0 + pt;
        const float* lrow = &logf[pt * 68];
        float mx = -1e30f;
        #pragma unroll 8
        for (int j = 0; j < OUTD; ++j) mx = fmaxf(mx, 3.0f * lrow[j]);
        float s = 0.0f, cx = 0.0f, cy = 0.0f;
        #pragma unroll 8
        for (int j = 0; j < OUTD; ++j) {
            float e = __expf(3.0f * lrow[j] - mx);
            s  += e;
            cx += e * (float)((j & 7) - 4);
            cy += e * (float)((j >> 3) - 4);
        }
        float conf = 1.0f / s;
        cx /= s; cy /= s;
        ull rm = rowmax[(size_t)b * NN + n];
        int m = (int)(~(unsigned int)(rm & 0xffffffffULL));
        ull cm = colmax[(size_t)b * NN + m];
        int back = (int)(~(unsigned int)(cm & 0xffffffffULL));
        bool mutual = (back == n);
        float sc = scales1[(size_t)b * NN + n];
        float x0 = kps1[((size_t)b * NN + n) * 2 + 0] + cx * sc;
        float y0 = kps1[((size_t)b * NN + n) * 2 + 1] + cy * sc;
        float x1 = kps2[((size_t)b * NN + m) * 2 + 0];
        float y1 = kps2[((size_t)b * NN + m) * 2 + 1];
        float* mt = out + ((size_t)b * NN + n) * 4;
        mt[0] = x0; mt[1] = y0; mt[2] = x1; mt[3] = y1;
        out[(size_t)BB * NN * 4 + (size_t)b * NN + n] =
            (mutual && conf > 0.25f) ? 1.0f : 0.0f;
    }
}

extern "C" void kernel_launch(void* const* d_in, const int* in_sizes, int n_in,
                              void* d_out, int out_size, void* d_ws, size_t ws_size,
                              hipStream_t stream)
{
    const float* f1  = (const float*)d_in[0];
    const float* f2  = (const float*)d_in[1];
    const float* kp1 = (const float*)d_in[2];
    const float* kp2 = (const float*)d_in[3];
    const float* sc1 = (const float*)d_in[4];
    const float* w1  = (const float*)d_in[5];
    const float* b1  = (const float*)d_in[6];
    const float* w2  = (const float*)d_in[7];
    const float* b2  = (const float*)d_in[8];
    const float* w3  = (const float*)d_in[9];
    const float* b3  = (const float*)d_in[10];
    const float* w4  = (const float*)d_in[11];
    const float* b4  = (const float*)d_in[12];
    const float* w5  = (const float*)d_in[13];
    const float* b5  = (const float*)d_in[14];

    ull* rowmax = (ull*)d_ws;
    ull* colmax = (ull*)((char*)d_ws + (size_t)BB * NN * 8);
    unsigned short* wt = (unsigned short*)((char*)d_ws + WS_WT_OFF);
    float* out = (float*)d_out;

    init_ws_kernel<<<(2 * BB * NN + 255) / 256, 256, 0, stream>>>(rowmax);
    convert_wt_kernel<<<(WT_TOTAL + 255) / 256, 256, 0, stream>>>(w1, w2, w3, w4, w5, wt);
    dim3 gA(NN / 128, CSPLIT, BB);
    sim_kernel<<<gA, 256, 0, stream>>>(f1, f2, rowmax, colmax);
    mlp_mfma_kernel<<<(BB * NN) / 64, 256, 0, stream>>>(
        f1, f2, kp1, kp2, sc1, b1, b2, b3, b4, b5, wt, rowmax, colmax, out);
}